// Round 4
// baseline (447.824 us; speedup 1.0000x reference)
//
#include <hip/hip_runtime.h>
#include <hip/hip_bf16.h>

#define D_MODEL 1024
#define NHEADS  16
#define HDIM    64
#define SEQ     2048
#define BATCH   2
#define MROWS   (BATCH * SEQ)   // 4096
#define CHELEM  ((size_t)BATCH * NHEADS * SEQ * HDIM)  // 4194304

typedef __bf16 bf16x8 __attribute__((ext_vector_type(8)));
typedef float  f32x4  __attribute__((ext_vector_type(4)));
typedef float  f32x16 __attribute__((ext_vector_type(16)));

__device__ __forceinline__ unsigned short f2bf(float f) {
  unsigned u = __builtin_bit_cast(unsigned, f);
  return (unsigned short)((u + 0x7fffu + ((u >> 16) & 1u)) >> 16);
}

__device__ __forceinline__ unsigned cvt_pk_bf16(float lo, float hi) {
  unsigned r;
  asm("v_cvt_pk_bf16_f32 %0, %1, %2" : "=v"(r) : "v"(lo), "v"(hi));
  return r;
}

__device__ __forceinline__ f32x4 mfma16(bf16x8 a, bf16x8 b, f32x4 c) {
  return __builtin_amdgcn_mfma_f32_16x16x32_bf16(a, b, c, 0, 0, 0);
}
__device__ __forceinline__ f32x16 mfma32(bf16x8 a, bf16x8 b, f32x16 c) {
  return __builtin_amdgcn_mfma_f32_32x32x16_bf16(a, b, c, 0, 0, 0);
}

__global__ void cvt_f32_bf16(const float* __restrict__ in,
                             unsigned short* __restrict__ out, int n4) {
  int i = blockIdx.x * blockDim.x + threadIdx.x;
  if (i >= n4) return;
  float4 v = reinterpret_cast<const float4*>(in)[i];
  ushort4 o;
  o.x = f2bf(v.x); o.y = f2bf(v.y); o.z = f2bf(v.z); o.w = f2bf(v.w);
  reinterpret_cast<ushort4*>(out)[i] = o;
}

// C = A[M,K] * Bt[N,K]^T + bias
// MODE 2: out f32 row-major [M,N]  (final projection, bias=b0)
// MODE 3: fused QKV: N=3072; chunk 0->Q [B,H,S,64], 1->K [B,H,S,64],
//         2->V^T [B,H,64,S]; outp = base of Q (chunks CHELEM apart)
template <int MODE>
__global__ __launch_bounds__(256) void gemm_bt2(
    const unsigned short* __restrict__ A,
    const unsigned short* __restrict__ Bt,
    const float* __restrict__ b0, const float* __restrict__ b1,
    const float* __restrict__ b2,
    void* __restrict__ outp, int M, int N, int K) {
  __shared__ __align__(16) unsigned short lA[128 * 32];
  __shared__ __align__(16) unsigned short lB[128 * 32];
  const int tid = threadIdx.x;
  const int m0 = blockIdx.y * 128, n0 = blockIdx.x * 128;
  const int lane = tid & 63, wid = tid >> 6;
  const int wr = wid >> 1, wc = wid & 1;
  const int fr = lane & 15, g = lane >> 4;
  const int lr = tid >> 2, lk = (tid & 3) * 8;

  const unsigned short* pa = A + (size_t)(m0 + lr) * K + lk;
  const unsigned short* pb = Bt + (size_t)(n0 + lr) * K + lk;

  f32x4 acc[4][4];
#pragma unroll
  for (int i = 0; i < 4; ++i)
#pragma unroll
    for (int j = 0; j < 4; ++j) acc[i][j] = (f32x4){0.f, 0.f, 0.f, 0.f};

  for (int kt = 0; kt < K; kt += 32) {
    uint4 a0 = *reinterpret_cast<const uint4*>(pa + kt);
    uint4 a1 = *reinterpret_cast<const uint4*>(pa + (size_t)64 * K + kt);
    uint4 b0u = *reinterpret_cast<const uint4*>(pb + kt);
    uint4 b1u = *reinterpret_cast<const uint4*>(pb + (size_t)64 * K + kt);
    __syncthreads();  // prior iteration's LDS reads complete
    *reinterpret_cast<uint4*>(&lA[lr * 32 + lk]) = a0;
    *reinterpret_cast<uint4*>(&lA[(lr + 64) * 32 + lk]) = a1;
    *reinterpret_cast<uint4*>(&lB[lr * 32 + lk]) = b0u;
    *reinterpret_cast<uint4*>(&lB[(lr + 64) * 32 + lk]) = b1u;
    __syncthreads();  // tile staged
    bf16x8 af[4], bfv[4];
#pragma unroll
    for (int i = 0; i < 4; ++i)
      af[i] = *reinterpret_cast<const bf16x8*>(
          &lA[(wr * 64 + i * 16 + fr) * 32 + g * 8]);
#pragma unroll
    for (int j = 0; j < 4; ++j)
      bfv[j] = *reinterpret_cast<const bf16x8*>(
          &lB[(wc * 64 + j * 16 + fr) * 32 + g * 8]);
#pragma unroll
    for (int i = 0; i < 4; ++i)
#pragma unroll
      for (int j = 0; j < 4; ++j)
        acc[i][j] = mfma16(af[i], bfv[j], acc[i][j]);
  }

  const int src = n0 >> 10;  // uniform per block (only used MODE 3)
  const float* bp = (MODE == 2) ? b0 : (src == 0 ? b0 : (src == 1 ? b1 : b2));
#pragma unroll
  for (int i = 0; i < 4; ++i)
#pragma unroll
    for (int j = 0; j < 4; ++j)
#pragma unroll
      for (int r = 0; r < 4; ++r) {
        int m = m0 + wr * 64 + i * 16 + g * 4 + r;
        int n = n0 + wc * 64 + j * 16 + fr;
        if (MODE == 2) {
          float val = acc[i][j][r] + bp[n];
          reinterpret_cast<float*>(outp)[(size_t)m * N + n] = val;
        } else {
          int within = n & 1023;
          float val = acc[i][j][r] + bp[within];
          int b = m >> 11, s = m & 2047;
          int hh = within >> 6, dh = within & 63;
          size_t idx;
          if (src != 2)
            idx = ((size_t)(b * NHEADS + hh) * SEQ + s) * HDIM + dh;
          else
            idx = ((size_t)(b * NHEADS + hh) * HDIM + dh) * SEQ + s;
          reinterpret_cast<unsigned short*>(outp)[(size_t)src * CHELEM + idx] =
              f2bf(val);
        }
      }
}

// ---------------- CONTROL ARM: round-1 proven attention (16x16) -------------
// Q,K: [B,H,S,64] bf16 ; Vt: [B,H,64,S] bf16 ; O: [B,S,1024] bf16
__global__ __launch_bounds__(64) void attn_fwd(
    const unsigned short* __restrict__ Q,
    const unsigned short* __restrict__ Km,
    const unsigned short* __restrict__ Vt,
    unsigned short* __restrict__ O) {
  const int lane = threadIdx.x;
  const int fr = lane & 15, g = lane >> 4;
  const int qt = blockIdx.x, h = blockIdx.y, b = blockIdx.z;
  const int bh = b * NHEADS + h;
  const int q0 = qt * 16;

  __shared__ unsigned short pl[16 * 32];

  const unsigned short* qb = Q + ((size_t)bh * SEQ + q0 + fr) * HDIM + g * 8;
  bf16x8 qa0 = *reinterpret_cast<const bf16x8*>(qb);
  bf16x8 qa1 = *reinterpret_cast<const bf16x8*>(qb + 32);

  const unsigned short* kb = Km + (size_t)bh * SEQ * HDIM;
  const unsigned short* vb = Vt + (size_t)bh * HDIM * SEQ;

  f32x4 oacc[4];
#pragma unroll
  for (int i = 0; i < 4; ++i) oacc[i] = (f32x4){0.f, 0.f, 0.f, 0.f};
  float mrow[4] = {-1e30f, -1e30f, -1e30f, -1e30f};
  float lrow[4] = {0.f, 0.f, 0.f, 0.f};

  const int nkt = (q0 + 16 + 31) >> 5;
  for (int kt = 0; kt < nkt; ++kt) {
    const int n0 = kt * 32;
    const unsigned short* kp0 = kb + (size_t)(n0 + fr) * HDIM + g * 8;
    const unsigned short* kp1 = kp0 + 16 * HDIM;
    bf16x8 k00 = *reinterpret_cast<const bf16x8*>(kp0);
    bf16x8 k01 = *reinterpret_cast<const bf16x8*>(kp0 + 32);
    bf16x8 k10 = *reinterpret_cast<const bf16x8*>(kp1);
    bf16x8 k11 = *reinterpret_cast<const bf16x8*>(kp1 + 32);
    f32x4 s0 = (f32x4){0.f, 0.f, 0.f, 0.f};
    f32x4 s1 = (f32x4){0.f, 0.f, 0.f, 0.f};
    s0 = mfma16(qa0, k00, s0);
    s0 = mfma16(qa1, k01, s0);
    s1 = mfma16(qa0, k10, s1);
    s1 = mfma16(qa1, k11, s1);

    float p0v[4], p1v[4];
#pragma unroll
    for (int r = 0; r < 4; ++r) {
      const int row = q0 + g * 4 + r;
      float sv0 = (n0 + fr <= row) ? s0[r] * 0.125f : -1e30f;
      float sv1 = (n0 + 16 + fr <= row) ? s1[r] * 0.125f : -1e30f;
      float tm = fmaxf(sv0, sv1);
#pragma unroll
      for (int msk = 1; msk < 16; msk <<= 1)
        tm = fmaxf(tm, __shfl_xor(tm, msk, 64));
      const float mn = fmaxf(mrow[r], tm);
      const float alpha = __expf(mrow[r] - mn);
      mrow[r] = mn;
      const float p0 = __expf(sv0 - mn);
      const float p1 = __expf(sv1 - mn);
      float ps = p0 + p1;
#pragma unroll
      for (int msk = 1; msk < 16; msk <<= 1)
        ps += __shfl_xor(ps, msk, 64);
      lrow[r] = lrow[r] * alpha + ps;
#pragma unroll
      for (int nf = 0; nf < 4; ++nf) oacc[nf][r] *= alpha;
      p0v[r] = p0;
      p1v[r] = p1;
    }
    __syncthreads();
#pragma unroll
    for (int r = 0; r < 4; ++r) {
      pl[(g * 4 + r) * 32 + fr] = f2bf(p0v[r]);
      pl[(g * 4 + r) * 32 + 16 + fr] = f2bf(p1v[r]);
    }
    __syncthreads();
    bf16x8 pa = *reinterpret_cast<const bf16x8*>(&pl[fr * 32 + g * 8]);
#pragma unroll
    for (int nf = 0; nf < 4; ++nf) {
      bf16x8 vf = *reinterpret_cast<const bf16x8*>(
          vb + (size_t)(nf * 16 + fr) * SEQ + n0 + g * 8);
      oacc[nf] = mfma16(pa, vf, oacc[nf]);
    }
  }

#pragma unroll
  for (int r = 0; r < 4; ++r) {
    const float inv = 1.f / lrow[r];
    const size_t base = ((size_t)b * SEQ + q0 + g * 4 + r) * D_MODEL + h * HDIM;
#pragma unroll
    for (int nf = 0; nf < 4; ++nf)
      O[base + nf * 16 + fr] = f2bf(oacc[nf][r] * inv);
  }
}

// ---------------- SHADOW ARM: 32x32 swapped-operand attention ---------------
__global__ __launch_bounds__(64) void attn_fwd2(
    const unsigned short* __restrict__ Q,
    const unsigned short* __restrict__ Km,
    const unsigned short* __restrict__ Vt,
    unsigned short* __restrict__ O) {
  const int lane = threadIdx.x;
  const int col = lane & 31;
  const int hi = lane >> 5;
  const int qt = blockIdx.x, h = blockIdx.y, b = blockIdx.z;
  const int bh = b * NHEADS + h;
  const int q0 = qt * 32;
  const int qg = q0 + col;

  const unsigned short* qb = Q + (size_t)bh * SEQ * HDIM;
  const unsigned short* kb = Km + (size_t)bh * SEQ * HDIM;
  const unsigned short* vb = Vt + (size_t)bh * HDIM * SEQ;

  bf16x8 qf[4];
#pragma unroll
  for (int c = 0; c < 4; ++c)
    qf[c] = *reinterpret_cast<const bf16x8*>(
        qb + (size_t)(q0 + col) * HDIM + c * 16 + hi * 8);

  f32x16 oacc[2];
#pragma unroll
  for (int db = 0; db < 2; ++db)
#pragma unroll
    for (int r = 0; r < 16; ++r) oacc[db][r] = 0.f;
  float m = -1e30f, lsum = 0.f;

  for (int kt = 0; kt <= qt; ++kt) {
    const int n0 = kt * 32;
    f32x16 s;
#pragma unroll
    for (int r = 0; r < 16; ++r) s[r] = 0.f;
    const unsigned short* kp = kb + (size_t)(n0 + col) * HDIM + hi * 8;
#pragma unroll
    for (int c = 0; c < 4; ++c) {
      bf16x8 kf = *reinterpret_cast<const bf16x8*>(kp + c * 16);
      s = mfma32(kf, qf[c], s);
    }
    float p[16];
    float tmax = -1e30f;
#pragma unroll
    for (int r = 0; r < 16; ++r) {
      int kg = n0 + (r & 3) + 8 * (r >> 2) + 4 * hi;
      float sv = (kg <= qg) ? s[r] * 0.125f : -1e30f;
      p[r] = sv;
      tmax = fmaxf(tmax, sv);
    }
    tmax = fmaxf(tmax, __shfl_xor(tmax, 32));
    const float mn = fmaxf(m, tmax);
    const float alpha = __expf(m - mn);
    m = mn;
    float ps = 0.f;
#pragma unroll
    for (int r = 0; r < 16; ++r) {
      p[r] = __expf(p[r] - mn);
      ps += p[r];
    }
    ps += __shfl_xor(ps, 32);
    lsum = lsum * alpha + ps;
    oacc[0] *= alpha;
    oacc[1] *= alpha;
    unsigned pk[8], po[8];
#pragma unroll
    for (int t = 0; t < 8; ++t) pk[t] = cvt_pk_bf16(p[2 * t], p[2 * t + 1]);
#pragma unroll
    for (int t = 0; t < 8; ++t) po[t] = (unsigned)__shfl_xor((int)pk[t], 32);
    uint4 b0u = hi ? make_uint4(po[2], po[3], pk[2], pk[3])
                   : make_uint4(pk[0], pk[1], po[0], po[1]);
    uint4 b1u = hi ? make_uint4(po[6], po[7], pk[6], pk[7])
                   : make_uint4(pk[4], pk[5], po[4], po[5]);
    bf16x8 P0 = __builtin_bit_cast(bf16x8, b0u);
    bf16x8 P1 = __builtin_bit_cast(bf16x8, b1u);
    const unsigned short* v0p = vb + (size_t)col * SEQ + n0 + hi * 8;
    const unsigned short* v1p = vb + (size_t)(32 + col) * SEQ + n0 + hi * 8;
    bf16x8 va0 = *reinterpret_cast<const bf16x8*>(v0p);
    bf16x8 va1 = *reinterpret_cast<const bf16x8*>(v0p + 16);
    bf16x8 vb0 = *reinterpret_cast<const bf16x8*>(v1p);
    bf16x8 vb1 = *reinterpret_cast<const bf16x8*>(v1p + 16);
    oacc[0] = mfma32(va0, P0, oacc[0]);
    oacc[0] = mfma32(va1, P1, oacc[0]);
    oacc[1] = mfma32(vb0, P0, oacc[1]);
    oacc[1] = mfma32(vb1, P1, oacc[1]);
  }

  __shared__ __align__(16) unsigned short pl[32 * 64];
  const float inv = 1.f / lsum;
#pragma unroll
  for (int db = 0; db < 2; ++db)
#pragma unroll
    for (int r = 0; r < 16; r += 2) {
      int d = db * 32 + (r & 3) + 8 * (r >> 2) + 4 * hi;
      unsigned pr = cvt_pk_bf16(oacc[db][r] * inv, oacc[db][r + 1] * inv);
      int byte = (col * 128 + d * 2) ^ ((col & 7) << 4);
      *reinterpret_cast<unsigned*>(reinterpret_cast<char*>(pl) + byte) = pr;
    }
  __syncthreads();
#pragma unroll
  for (int t = 0; t < 4; ++t) {
    int idx = t * 64 + lane;
    int q = idx >> 3, gr = idx & 7;
    int byte = (q * 128 + gr * 16) ^ ((q & 7) << 4);
    uint4 v = *reinterpret_cast<const uint4*>(
        reinterpret_cast<const char*>(pl) + byte);
    *reinterpret_cast<uint4*>(O + ((size_t)b * SEQ + q0 + q) * D_MODEL +
                              h * 64 + gr * 8) = v;
  }
}

extern "C" void kernel_launch(void* const* d_in, const int* in_sizes, int n_in,
                              void* d_out, int out_size, void* d_ws,
                              size_t ws_size, hipStream_t stream) {
  const float* x  = (const float*)d_in[0];
  const float* wq = (const float*)d_in[1];
  const float* bq = (const float*)d_in[2];
  const float* wk = (const float*)d_in[3];
  const float* bk = (const float*)d_in[4];
  const float* wv = (const float*)d_in[5];
  const float* bv = (const float*)d_in[6];
  const float* wo = (const float*)d_in[7];
  const float* bo = (const float*)d_in[8];
  float* out = (float*)d_out;

  char* w = (char*)d_ws;
  unsigned short* xb    = (unsigned short*)w; w += (size_t)MROWS * D_MODEL * 2;
  unsigned short* wqkvb = (unsigned short*)w; w += (size_t)3 * D_MODEL * D_MODEL * 2;
  unsigned short* wob   = (unsigned short*)w; w += (size_t)D_MODEL * D_MODEL * 2;
  unsigned short* Qb    = (unsigned short*)w; w += CHELEM * 2 * 3;  // Q,K,Vt
  unsigned short* Ob    = (unsigned short*)w; w += (size_t)MROWS * D_MODEL * 2;
  unsigned short* Kb  = Qb + CHELEM;
  unsigned short* Vtb = Qb + 2 * CHELEM;

  {
    int n4 = MROWS * D_MODEL / 4;
    cvt_f32_bf16<<<n4 / 256, 256, 0, stream>>>(x, xb, n4);
  }
  {
    int n4 = D_MODEL * D_MODEL / 4;
    cvt_f32_bf16<<<n4 / 256, 256, 0, stream>>>(wq, wqkvb, n4);
    cvt_f32_bf16<<<n4 / 256, 256, 0, stream>>>(wk, wqkvb + (size_t)D_MODEL * D_MODEL, n4);
    cvt_f32_bf16<<<n4 / 256, 256, 0, stream>>>(wv, wqkvb + (size_t)2 * D_MODEL * D_MODEL, n4);
    cvt_f32_bf16<<<n4 / 256, 256, 0, stream>>>(wo, wob, n4);
  }

  // fused QKV projection: N = 3072
  gemm_bt2<3><<<dim3(3 * D_MODEL / 128, MROWS / 128), 256, 0, stream>>>(
      xb, wqkvb, bq, bk, bv, Qb, MROWS, 3 * D_MODEL, D_MODEL);

  // SHADOW: new attention writes into dead xb region (timed/profiled, unused)
  attn_fwd2<<<dim3(SEQ / 32, NHEADS, BATCH), 64, 0, stream>>>(Qb, Kb, Vtb, xb);

  // CONTROL: proven round-1 attention feeds the real output path
  attn_fwd<<<dim3(SEQ / 16, NHEADS, BATCH), 64, 0, stream>>>(Qb, Kb, Vtb, Ob);

  gemm_bt2<2><<<dim3(D_MODEL / 128, MROWS / 128), 256, 0, stream>>>(
      Ob, wob, bo, bo, bo, out, MROWS, D_MODEL, D_MODEL);
}

// Round 5
// 258.705 us; speedup vs baseline: 1.7310x; 1.7310x over previous
//
#include <hip/hip_runtime.h>
#include <hip/hip_bf16.h>

#define D_MODEL 1024
#define NHEADS  16
#define HDIM    64
#define SEQ     2048
#define BATCH   2
#define MROWS   (BATCH * SEQ)   // 4096
#define CHELEM  ((size_t)BATCH * NHEADS * SEQ * HDIM)  // 4194304

typedef __bf16 bf16x8 __attribute__((ext_vector_type(8)));
typedef float  f32x4  __attribute__((ext_vector_type(4)));

__device__ __forceinline__ unsigned short f2bf(float f) {
  unsigned u = __builtin_bit_cast(unsigned, f);
  return (unsigned short)((u + 0x7fffu + ((u >> 16) & 1u)) >> 16);
}

__device__ __forceinline__ f32x4 mfma16(bf16x8 a, bf16x8 b, f32x4 c) {
  return __builtin_amdgcn_mfma_f32_16x16x32_bf16(a, b, c, 0, 0, 0);
}

__device__ __forceinline__ void gll16(const unsigned short* g, unsigned short* l) {
  __builtin_amdgcn_global_load_lds(
      (const __attribute__((address_space(1))) unsigned*)g,
      (__attribute__((address_space(3))) unsigned*)l, 16, 0, 0);
}

__global__ void cvt_f32_bf16(const float* __restrict__ in,
                             unsigned short* __restrict__ out, int n4) {
  int i = blockIdx.x * blockDim.x + threadIdx.x;
  if (i >= n4) return;
  float4 v = reinterpret_cast<const float4*>(in)[i];
  ushort4 o;
  o.x = f2bf(v.x); o.y = f2bf(v.y); o.z = f2bf(v.z); o.w = f2bf(v.w);
  reinterpret_cast<ushort4*>(out)[i] = o;
}

// C = A[M,K] * Bt[N,K]^T + bias  (global_load_lds staging, m97 pattern)
// MODE 2: out f32 row-major [M,N]  (final projection, bias=b0)
// MODE 3: fused QKV: N=3072; chunk 0->Q [B,H,S,64], 1->K [B,H,S,64],
//         2->V^T [B,H,64,S]; outp = base of Q (chunks CHELEM apart)
template <int MODE>
__global__ __launch_bounds__(256) void gemm_bt2(
    const unsigned short* __restrict__ A,
    const unsigned short* __restrict__ Bt,
    const float* __restrict__ b0, const float* __restrict__ b1,
    const float* __restrict__ b2,
    void* __restrict__ outp, int M, int N, int K) {
  __shared__ __align__(16) unsigned short lA[128 * 32];
  __shared__ __align__(16) unsigned short lB[128 * 32];
  const int tid = threadIdx.x;
  const int m0 = blockIdx.y * 128, n0 = blockIdx.x * 128;
  const int lane = tid & 63, wid = tid >> 6;
  const int wr = wid >> 1, wc = wid & 1;
  const int fr = lane & 15, g = lane >> 4;

  // staging: wave wid stages rows [wid*32, wid*32+32) of both tiles.
  // LDS dest is wave-uniform base + lane*16B (linear); global src per-lane.
  const int srow = wid * 32 + (lane >> 2);
  const int scol = (lane & 3) * 8;
  const unsigned short* gA = A + (size_t)(m0 + srow) * K + scol;
  const unsigned short* gB = Bt + (size_t)(n0 + srow) * K + scol;
  unsigned short* lAw = lA + wid * 1024;
  unsigned short* lBw = lB + wid * 1024;

  f32x4 acc[4][4];
#pragma unroll
  for (int i = 0; i < 4; ++i)
#pragma unroll
    for (int j = 0; j < 4; ++j) acc[i][j] = (f32x4){0.f, 0.f, 0.f, 0.f};

  for (int kt = 0; kt < K; kt += 32) {
    gll16(gA + kt, lAw);
    gll16(gA + (size_t)16 * K + kt, lAw + 512);
    gll16(gB + kt, lBw);
    gll16(gB + (size_t)16 * K + kt, lBw + 512);
    __syncthreads();  // drains vmcnt -> staged data visible
    bf16x8 af[4], bfv[4];
#pragma unroll
    for (int i = 0; i < 4; ++i)
      af[i] = *reinterpret_cast<const bf16x8*>(
          &lA[(wr * 64 + i * 16 + fr) * 32 + g * 8]);
#pragma unroll
    for (int j = 0; j < 4; ++j)
      bfv[j] = *reinterpret_cast<const bf16x8*>(
          &lB[(wc * 64 + j * 16 + fr) * 32 + g * 8]);
#pragma unroll
    for (int i = 0; i < 4; ++i)
#pragma unroll
      for (int j = 0; j < 4; ++j)
        acc[i][j] = mfma16(af[i], bfv[j], acc[i][j]);
    __syncthreads();  // all reads done before next stage overwrites
  }

  const int src = n0 >> 10;  // uniform per block (only used MODE 3)
  const float* bp = (MODE == 2) ? b0 : (src == 0 ? b0 : (src == 1 ? b1 : b2));
#pragma unroll
  for (int i = 0; i < 4; ++i)
#pragma unroll
    for (int j = 0; j < 4; ++j)
#pragma unroll
      for (int r = 0; r < 4; ++r) {
        int m = m0 + wr * 64 + i * 16 + g * 4 + r;
        int n = n0 + wc * 64 + j * 16 + fr;
        if (MODE == 2) {
          float val = acc[i][j][r] + bp[n];
          reinterpret_cast<float*>(outp)[(size_t)m * N + n] = val;
        } else {
          int within = n & 1023;
          float val = acc[i][j][r] + bp[within];
          int b = m >> 11, s = m & 2047;
          int hh = within >> 6, dh = within & 63;
          size_t idx;
          if (src != 2)
            idx = ((size_t)(b * NHEADS + hh) * SEQ + s) * HDIM + dh;
          else
            idx = ((size_t)(b * NHEADS + hh) * HDIM + dh) * SEQ + s;
          reinterpret_cast<unsigned short*>(outp)[(size_t)src * CHELEM + idx] =
              f2bf(val);
        }
      }
}

// Flash attention, proven 16x16 fragment conventions. 4 independent waves per
// block, complementary q-tiles for perfect load balance. KVBLK=64, no barriers
// (per-wave LDS slices; different waves have different trip counts!).
// Q,K: [B,H,S,64] bf16 ; Vt: [B,H,64,S] bf16 ; O: [B,S,1024] bf16
__global__ __launch_bounds__(256) void attn_fwd3(
    const unsigned short* __restrict__ Q,
    const unsigned short* __restrict__ Km,
    const unsigned short* __restrict__ Vt,
    unsigned short* __restrict__ O) {
  const int tid = threadIdx.x;
  const int lane = tid & 63, wid = tid >> 6;
  const int fr = lane & 15, g = lane >> 4;
  const int bq = blockIdx.x, h = blockIdx.y, b = blockIdx.z;
  // balanced complementary mapping: {bq, 63-bq, 64+bq, 127-bq}, sum const
  const int qt = (wid == 0) ? bq : (wid == 1) ? 63 - bq
               : (wid == 2) ? 64 + bq : 127 - bq;
  const int bh = b * NHEADS + h;
  const int q0 = qt * 16;

  __shared__ __align__(16) unsigned short pl[4][16 * 64];  // 2KB/wave, swizzled
  char* plw = reinterpret_cast<char*>(pl[wid]);

  const unsigned short* qb = Q + ((size_t)bh * SEQ + q0 + fr) * HDIM + g * 8;
  bf16x8 qa0 = *reinterpret_cast<const bf16x8*>(qb);
  bf16x8 qa1 = *reinterpret_cast<const bf16x8*>(qb + 32);

  const unsigned short* kb = Km + (size_t)bh * SEQ * HDIM;
  const unsigned short* vb = Vt + (size_t)bh * HDIM * SEQ;

  f32x4 oacc[4];
#pragma unroll
  for (int i = 0; i < 4; ++i) oacc[i] = (f32x4){0.f, 0.f, 0.f, 0.f};
  float mrow[4] = {-1e30f, -1e30f, -1e30f, -1e30f};
  float lrow[4] = {0.f, 0.f, 0.f, 0.f};

  const int nkt = (q0 + 16 + 63) >> 6;
  for (int kt = 0; kt < nkt; ++kt) {
    const int n0 = kt * 64;
    // K fragments: key = n0 + c*16 + fr, d = {g*8, 32+g*8}+j
    const unsigned short* kp = kb + (size_t)(n0 + fr) * HDIM + g * 8;
    bf16x8 kf0[4], kf1[4];
#pragma unroll
    for (int c = 0; c < 4; ++c) {
      kf0[c] = *reinterpret_cast<const bf16x8*>(kp + c * 16 * HDIM);
      kf1[c] = *reinterpret_cast<const bf16x8*>(kp + c * 16 * HDIM + 32);
    }
    // V fragments hoisted: B[k = blk*32+g*8+j][d-col = nf*16+fr]
    bf16x8 vf[2][4];
#pragma unroll
    for (int nf = 0; nf < 4; ++nf) {
      const unsigned short* vp = vb + (size_t)(nf * 16 + fr) * SEQ + n0 + g * 8;
      vf[0][nf] = *reinterpret_cast<const bf16x8*>(vp);
      vf[1][nf] = *reinterpret_cast<const bf16x8*>(vp + 32);
    }
    // QK^T: s[c] rows q = q0+g*4+r, cols key = n0+c*16+fr
    f32x4 s[4];
#pragma unroll
    for (int c = 0; c < 4; ++c) {
      s[c] = (f32x4){0.f, 0.f, 0.f, 0.f};
      s[c] = mfma16(qa0, kf0[c], s[c]);
      s[c] = mfma16(qa1, kf1[c], s[c]);
    }
    // online softmax, 4 rows/lane-group, 64 keys amortized per reduce
#pragma unroll
    for (int r = 0; r < 4; ++r) {
      const int row = q0 + g * 4 + r;
      float sv[4];
      float tm = -1e30f;
#pragma unroll
      for (int c = 0; c < 4; ++c) {
        sv[c] = (n0 + c * 16 + fr <= row) ? s[c][r] * 0.125f : -1e30f;
        tm = fmaxf(tm, sv[c]);
      }
#pragma unroll
      for (int msk = 1; msk < 16; msk <<= 1)
        tm = fmaxf(tm, __shfl_xor(tm, msk, 64));
      const float mn = fmaxf(mrow[r], tm);
      const float alpha = __expf(mrow[r] - mn);
      mrow[r] = mn;
      float ps = 0.f;
      float p[4];
#pragma unroll
      for (int c = 0; c < 4; ++c) {
        p[c] = __expf(sv[c] - mn);
        ps += p[c];
      }
#pragma unroll
      for (int msk = 1; msk < 16; msk <<= 1)
        ps += __shfl_xor(ps, msk, 64);
      lrow[r] = lrow[r] * alpha + ps;
#pragma unroll
      for (int nf = 0; nf < 4; ++nf) oacc[nf][r] *= alpha;
      const int rl = g * 4 + r;
#pragma unroll
      for (int c = 0; c < 4; ++c) {
        int byte = (rl * 128 + (c * 16 + fr) * 2) ^ ((rl & 7) << 4);
        *reinterpret_cast<unsigned short*>(plw + byte) = f2bf(p[c]);
      }
    }
    // PV: A[q=fr][k=blk*32+g*8+j] from swizzled LDS (same-wave, no barrier)
#pragma unroll
    for (int blk = 0; blk < 2; ++blk) {
      int byte = (fr * 128 + blk * 64 + g * 16) ^ ((fr & 7) << 4);
      bf16x8 pa = *reinterpret_cast<const bf16x8*>(plw + byte);
#pragma unroll
      for (int nf = 0; nf < 4; ++nf)
        oacc[nf] = mfma16(pa, vf[blk][nf], oacc[nf]);
    }
  }

#pragma unroll
  for (int r = 0; r < 4; ++r) {
    const float inv = 1.f / lrow[r];
    const size_t base = ((size_t)b * SEQ + q0 + g * 4 + r) * D_MODEL + h * HDIM;
#pragma unroll
    for (int nf = 0; nf < 4; ++nf)
      O[base + nf * 16 + fr] = f2bf(oacc[nf][r] * inv);
  }
}

extern "C" void kernel_launch(void* const* d_in, const int* in_sizes, int n_in,
                              void* d_out, int out_size, void* d_ws,
                              size_t ws_size, hipStream_t stream) {
  const float* x  = (const float*)d_in[0];
  const float* wq = (const float*)d_in[1];
  const float* bq = (const float*)d_in[2];
  const float* wk = (const float*)d_in[3];
  const float* bk = (const float*)d_in[4];
  const float* wv = (const float*)d_in[5];
  const float* bv = (const float*)d_in[6];
  const float* wo = (const float*)d_in[7];
  const float* bo = (const float*)d_in[8];
  float* out = (float*)d_out;

  char* w = (char*)d_ws;
  unsigned short* xb    = (unsigned short*)w; w += (size_t)MROWS * D_MODEL * 2;
  unsigned short* wqkvb = (unsigned short*)w; w += (size_t)3 * D_MODEL * D_MODEL * 2;
  unsigned short* wob   = (unsigned short*)w; w += (size_t)D_MODEL * D_MODEL * 2;
  unsigned short* Qb    = (unsigned short*)w; w += CHELEM * 2 * 3;  // Q,K,Vt
  unsigned short* Ob    = (unsigned short*)w; w += (size_t)MROWS * D_MODEL * 2;
  unsigned short* Kb  = Qb + CHELEM;
  unsigned short* Vtb = Qb + 2 * CHELEM;

  {
    int n4 = MROWS * D_MODEL / 4;
    cvt_f32_bf16<<<n4 / 256, 256, 0, stream>>>(x, xb, n4);
  }
  {
    int n4 = D_MODEL * D_MODEL / 4;
    cvt_f32_bf16<<<n4 / 256, 256, 0, stream>>>(wq, wqkvb, n4);
    cvt_f32_bf16<<<n4 / 256, 256, 0, stream>>>(wk, wqkvb + (size_t)D_MODEL * D_MODEL, n4);
    cvt_f32_bf16<<<n4 / 256, 256, 0, stream>>>(wv, wqkvb + (size_t)2 * D_MODEL * D_MODEL, n4);
    cvt_f32_bf16<<<n4 / 256, 256, 0, stream>>>(wo, wob, n4);
  }

  // fused QKV projection: N = 3072
  gemm_bt2<3><<<dim3(3 * D_MODEL / 128, MROWS / 128), 256, 0, stream>>>(
      xb, wqkvb, bq, bk, bv, Qb, MROWS, 3 * D_MODEL, D_MODEL);

  attn_fwd3<<<dim3(SEQ / 64, NHEADS, BATCH), 256, 0, stream>>>(Qb, Kb, Vtb, Ob);

  gemm_bt2<2><<<dim3(D_MODEL / 128, MROWS / 128), 256, 0, stream>>>(
      Ob, wob, bo, bo, bo, out, MROWS, D_MODEL, D_MODEL);
}